// Round 17
// baseline (190.768 us; speedup 1.0000x reference)
//
#include <hip/hip_runtime.h>
#include <hip/hip_bf16.h>

#define B_ 8
#define S_ 1024
#define D_ 1024
#define H_ 16
#define DK_ 64
#define M_ (B_*S_)

// 0.125 * log2(e): folds the 1/sqrt(dk) scale AND the exp->exp2 conversion into Q
#define QSCALE 0.1803368801111904f

typedef __attribute__((ext_vector_type(4))) float f32x4;
typedef __attribute__((ext_vector_type(8))) short bf16x8;
typedef __attribute__((ext_vector_type(4))) short s16x4;
typedef __hip_bfloat16 bf16;
typedef unsigned long long ull;

#define GLOAD_LDS16(gp, lp) __builtin_amdgcn_global_load_lds( \
    (const __attribute__((address_space(1))) void*)(gp), \
    (__attribute__((address_space(3))) void*)(lp), 16, 0, 0)

#define SBAR()   asm volatile("s_barrier" ::: "memory")
#define VMCNT(n) asm volatile("s_waitcnt vmcnt(" #n ")" ::: "memory")

__device__ __forceinline__ bf16x8 ld8(const bf16* p){ return *(const bf16x8*)p; }

__device__ __forceinline__ short bf16bits(float f){
  bf16 h = __float2bfloat16(f);
  return __builtin_bit_cast(short, h);
}
__device__ __forceinline__ float tof(short b){
  unsigned u = ((unsigned)(unsigned short)b) << 16;
  return __builtin_bit_cast(float, u);
}
// packed f32x2 -> bf16x2 (RNE)
__device__ __forceinline__ int cvtpk(float a, float b){
  int r; asm("v_cvt_pk_bf16_f32 %0, %1, %2" : "=v"(r) : "v"(a), "v"(b)); return r;
}

// swizzled LDS fragment read: tile rows of 128B, XOR swizzle byte^=((row&7)<<4)
__device__ __forceinline__ bf16x8 ld8swz(const bf16* base, int row, int colb){
  int sw = colb ^ ((row & 7) << 4);
  return *(const bf16x8*)((const char*)base + row*128 + sw);
}

// ---------------- merged casts: X (blocks 0..4095) + 4 weight mats (4096..6143) ----------------
__global__ __launch_bounds__(256) void cast_all(const float* __restrict__ X,
    const float* __restrict__ w0, const float* __restrict__ w1,
    const float* __restrict__ w2, const float* __restrict__ w3,
    bf16* __restrict__ Xout, bf16* __restrict__ Wout){
  int bid = blockIdx.x;
  if (bid < 4096){
    int i = (bid*256 + threadIdx.x)*8;
    f32x4 a = *(const f32x4*)(X+i);
    f32x4 b = *(const f32x4*)(X+i+4);
    bf16x8 o;
    #pragma unroll
    for (int c=0;c<4;c++){ o[c] = bf16bits(a[c]); o[c+4] = bf16bits(b[c]); }
    *(bf16x8*)(Xout+i) = o;
  } else {
    int bb = bid - 4096;
    int sel = bb >> 9;
    const float* src = (sel==0)?w0:((sel==1)?w1:((sel==2)?w2:w3));
    int i = (((bb & 511)*256) + threadIdx.x)*8;
    f32x4 a = *(const f32x4*)(src+i);
    f32x4 b = *(const f32x4*)(src+i+4);
    bf16x8 o;
    #pragma unroll
    for (int c=0;c<4;c++){ o[c] = bf16bits(a[c]); o[c+4] = bf16bits(b[c]); }
    *(bf16x8*)(Wout + ((size_t)sel<<20) + i) = o;
  }
}

// ---------------- V column mean (for fully-masked rows); permutation-invariant ----------------
__global__ __launch_bounds__(256) void vmean_kernel(const bf16* __restrict__ Vt_g,
                                                    float* __restrict__ vmean){
  int r = blockIdx.x*4 + (threadIdx.x>>6);
  int lane = threadIdx.x & 63;
  const bf16* p = Vt_g + (((size_t)r)<<10) + lane*16;
  bf16x8 a = ld8(p), c = ld8(p+8);
  float s = 0.f;
  #pragma unroll
  for (int e=0;e<8;e++) s += tof(a[e]) + tof(c[e]);
  #pragma unroll
  for (int off=1;off<64;off<<=1) s += __shfl_xor(s, off);
  if (lane==0) vmean[r] = s * (1.f/1024.f);
}

// ---------------- GEMM: C = A * W^T (+bias), 128x128 tile, pipelined staging ----------------
// MODE 0 (z=0 Q pre-scaled / z=1 K): SWAPPED mfma(W,X) -> col(lr)=token, row(j)=feature;
//          epilogue packs 4 consecutive dd into s16x4 (8B stores, vector bias).
// MODE 1 (O): swapped; epilogue = acc + bias4 + resid4 (f32x4 reads) -> bf16 X2 (s16x4 stores).
// MODE 2 (V): original orientation + LDS transpose -> sigma-permuted V^T [B,H,dk,S].
template<int MODE>
__global__ __launch_bounds__(256) void gemm128(
    const bf16* __restrict__ A,
    const bf16* __restrict__ W0, const bf16* __restrict__ W1,
    const float* __restrict__ b0, const float* __restrict__ b1,
    bf16* __restrict__ o0, bf16* __restrict__ o1,
    const float* __restrict__ resid)
{
  const bf16* Wsel = W0; const float* bsel = b0;
  if (MODE==0 && blockIdx.z == 1){ Wsel = W1; bsel = b1; }
  __shared__ bf16 smem[4*128*64];   // 64KB: buf0{A,B}, buf1{A,B}
  const int tid = threadIdx.x, wid = tid>>6, lane = tid&63;
  const int lr = lane&15, lg = lane>>4;
  const int m0 = blockIdx.x*128, n0 = blockIdx.y*128;
  const int wr = wid>>1, wc = wid&1;
  f32x4 acc[4][4] = {};

  auto STAGE = [&](int k0, int bsel_){
    #pragma unroll
    for (int c=0;c<4;c++){
      int ldsoff = ((c<<2)|wid)<<10;
      int off = ldsoff + (lane<<4);
      int row = off>>7;
      int colb = (off&127) ^ ((row&7)<<4);
      GLOAD_LDS16(A   + (((size_t)(m0+row))<<10) + k0 + (colb>>1), (char*)smem + bsel_*32768 + ldsoff);
      GLOAD_LDS16(Wsel+ (((size_t)(n0+row))<<10) + k0 + (colb>>1), (char*)smem + bsel_*32768 + 16384 + ldsoff);
    }
  };

  STAGE(0, 0);
  int cur = 0;
  for (int kt=0; kt<16; kt++){
    if (kt < 15){ STAGE((kt+1)<<6, cur^1); VMCNT(8); }
    else        { VMCNT(0); }
    SBAR();
    __builtin_amdgcn_sched_barrier(0);
    const bf16* Asb = smem + cur*16384;
    const bf16* Bsb = Asb + 8192;
    bf16x8 af[4][2], bfv[4][2];
    #pragma unroll
    for (int m=0;m<4;m++){
      int row = wr*64 + m*16 + lr;
      af[m][0] = ld8swz(Asb, row, lg*16);
      af[m][1] = ld8swz(Asb, row, lg*16 + 64);
    }
    #pragma unroll
    for (int n=0;n<4;n++){
      int row = wc*64 + n*16 + lr;
      bfv[n][0] = ld8swz(Bsb, row, lg*16);
      bfv[n][1] = ld8swz(Bsb, row, lg*16 + 64);
    }
    #pragma unroll
    for (int m=0;m<4;m++)
      #pragma unroll
      for (int n=0;n<4;n++){
        if (MODE==2){
          acc[m][n] = __builtin_amdgcn_mfma_f32_16x16x32_bf16(af[m][0], bfv[n][0], acc[m][n],0,0,0);
          acc[m][n] = __builtin_amdgcn_mfma_f32_16x16x32_bf16(af[m][1], bfv[n][1], acc[m][n],0,0,0);
        } else {
          // swapped: col(lr) = token row of A, row(lg*4+j) = W row (output feature)
          acc[m][n] = __builtin_amdgcn_mfma_f32_16x16x32_bf16(bfv[n][0], af[m][0], acc[m][n],0,0,0);
          acc[m][n] = __builtin_amdgcn_mfma_f32_16x16x32_bf16(bfv[n][1], af[m][1], acc[m][n],0,0,0);
        }
      }
    __builtin_amdgcn_sched_barrier(0);
    SBAR();
    cur ^= 1;
  }

  if (MODE==0){
    bf16* osel = (blockIdx.z==0) ? o0 : o1;
    const float qs = (blockIdx.z==0) ? QSCALE : 1.0f;
    #pragma unroll
    for (int m=0;m<4;m++){
      int row_tok = m0 + wr*64 + m*16 + lr;
      int bb = row_tok>>10, ss = row_tok&1023;
      #pragma unroll
      for (int n=0;n<4;n++){
        int col0 = n0 + wc*64 + n*16 + lg*4;
        int h = col0>>6, dd0 = col0&63;
        f32x4 bias4 = *(const f32x4*)(bsel + col0);
        s16x4 pk;
        #pragma unroll
        for (int j=0;j<4;j++) pk[j] = bf16bits((acc[m][n][j] + bias4[j])*qs);
        *(s16x4*)(osel + ((((size_t)bb*H_ + h)<<10) + ss)*DK_ + dd0) = pk;
      }
    }
  } else if (MODE==1){
    // xout (bf16 X2) = acc + bias + resid
    #pragma unroll
    for (int m=0;m<4;m++){
      int row_tok = m0 + wr*64 + m*16 + lr;
      #pragma unroll
      for (int n=0;n<4;n++){
        int col0 = n0 + wc*64 + n*16 + lg*4;
        f32x4 bias4 = *(const f32x4*)(b0 + col0);
        f32x4 rv = *(const f32x4*)(resid + (((size_t)row_tok)<<10) + col0);
        s16x4 pk;
        #pragma unroll
        for (int j=0;j<4;j++) pk[j] = bf16bits(acc[m][n][j] + bias4[j] + rv[j]);
        *(s16x4*)(o0 + (((size_t)row_tok)<<10) + col0) = pk;
      }
    }
  } else {
    // MODE 2: V^T via LDS transpose, sigma-permuted split write
    __syncthreads();
    #pragma unroll
    for (int n=0;n<4;n++){
      int c = wc*64 + n*16 + lr;
      float bias = b0[n0 + c];
      #pragma unroll
      for (int m=0;m<4;m++){
        int r0 = wr*64 + m*16 + lg*4;
        s16x4 pk;
        #pragma unroll
        for (int j=0;j<4;j++) pk[j] = bf16bits(acc[m][n][j] + bias);
        *(s16x4*)((char*)smem + c*256 + ((r0*2) ^ ((c&7)<<4))) = pk;
      }
    }
    __syncthreads();
    #pragma unroll
    for (int q=0;q<8;q++){
      int idx = tid + q*256;
      int c = idx>>4, r8 = idx&15;
      bf16x8 vv = *(const bf16x8*)((char*)smem + c*256 + ((r8*16) ^ ((c&7)<<4)));
      int col = n0 + c;  int h = col>>6, dd = col&63;
      int row0 = m0 + r8*8;  int bb = row0>>10, s0 = row0&1023;
      int a = (s0>>3)&3;
      int O = 16*(a&1) + 4*(a>>1);
      bf16* dst = o0 + ((((size_t)bb*H_ + h)*DK_ + dd)<<10) + (s0 & ~31) + O;
      s16x4 lo, hi;
      lo[0]=vv[0]; lo[1]=vv[1]; lo[2]=vv[2]; lo[3]=vv[3];
      hi[0]=vv[4]; hi[1]=vv[5]; hi[2]=vv[6]; hi[3]=vv[7];
      *(s16x4*)dst       = lo;
      *(s16x4*)(dst + 8) = hi;
    }
  }
}

// ---------------- fused causal attention: swapped-QK, in-register P (r16 benched) ----------------
__global__ __launch_bounds__(512) void attn_kernel(
    const bf16* __restrict__ Q, const bf16* __restrict__ K, const bf16* __restrict__ Vt_g,
    const int* __restrict__ seqm, const float* __restrict__ vmean, bf16* __restrict__ ctxout)
{
  __shared__ bf16 Ks[2][64*64];
  __shared__ bf16 Vs[2][64*64];
  __shared__ int msk[1024];
  const int tid = threadIdx.x, wid = tid>>6, lane = tid&63;
  const int lr = lane&15, lg = lane>>4;
  const int bh = blockIdx.x, xb = blockIdx.y;
  const int b = bh>>4, h = bh&15;
  const bf16* Qb  = Q    + (size_t)bh * S_ * DK_;
  const bf16* Kb  = K    + (size_t)bh * S_ * DK_;
  const bf16* Vtb = Vt_g + (size_t)bh * DK_ * S_;
  for (int i=tid;i<1024;i+=512) msk[i] = seqm[b*1024+i];

  const int g0 = 8*xb + wid;
  const int rb0 = g0*16;
  const int rb1 = (63 - g0)*16;
  bf16x8 qf[2][2];
  {
    const bf16* p0 = Qb + (size_t)(rb0+lr)*DK_ + lg*8;
    const bf16* p1 = Qb + (size_t)(rb1+lr)*DK_ + lg*8;
    qf[0][0] = ld8(p0); qf[0][1] = ld8(p0+32);
    qf[1][0] = ld8(p1); qf[1][1] = ld8(p1+32);
  }
  f32x4 cacc[2][4] = {};
  float lsum[2] = {0.f, 0.f};

  auto STAGE = [&](int t, int bsel){
    const int j0 = t*64;
    int off = (wid<<10) + (lane<<4);
    int row = off>>7;
    int colb = (off&127) ^ ((row&7)<<4);
    GLOAD_LDS16(Kb  + (size_t)(j0+row)*DK_ + (colb>>1), (char*)&Ks[bsel][0] + (wid<<10));
    GLOAD_LDS16(Vtb + (((size_t)row)<<10) + j0 + (colb>>1), (char*)&Vs[bsel][0] + (wid<<10));
  };

  STAGE(0, 0);
  __syncthreads();

  const int bnt = ((1023 - 128*xb) >> 6) + 1;

  int cur = 0;
  for (int t=0; t<bnt; t++){
    VMCNT(0);
    SBAR();
    if (t+1 < bnt) STAGE(t+1, cur^1);
    const int j0 = t*64;
    if (j0 <= rb1 + 15){
      const bool act0 = (j0 <= rb0 + 15);
      ull bt = __ballot(msk[j0 + lane] != 0);
      unsigned btl = (unsigned)bt, bth = (unsigned)(bt >> 32);

      bf16x8 kf[4][2];
      #pragma unroll
      for (int nf=0;nf<4;nf++){
        kf[nf][0] = ld8swz(&Ks[cur][0], nf*16+lr, lg*16);
        kf[nf][1] = ld8swz(&Ks[cur][0], nf*16+lr, lg*16 + 64);
      }

      bf16x8 pf[2][2];
      #pragma unroll
      for (int mf=0;mf<2;mf++){
        if (mf==0 && !act0) continue;
        const int rbm = mf ? rb1 : rb0;
        const bool diag = (j0 + 63 > rbm);
        const int qrel = rbm + lr - j0;
        f32x4 sc[4] = {};
        __builtin_amdgcn_s_setprio(1);
        #pragma unroll
        for (int nf=0;nf<4;nf++){
          sc[nf] = __builtin_amdgcn_mfma_f32_16x16x32_bf16(kf[nf][0], qf[mf][0], sc[nf],0,0,0);
          sc[nf] = __builtin_amdgcn_mfma_f32_16x16x32_bf16(kf[nf][1], qf[mf][1], sc[nf],0,0,0);
        }
        __builtin_amdgcn_s_setprio(0);
        float ls = 0.f;
        #pragma unroll
        for (int nf=0;nf<4;nf++){
          unsigned hb2 = (nf<2) ? btl : bth;
          #pragma unroll
          for (int j=0;j<4;j++){
            float p = exp2f(sc[nf][j]);
            bool ok = ((hb2 >> (16*(nf&1) + 4*lg + j)) & 1u) != 0u;
            if (diag) ok = ok && (16*nf + 4*lg + j <= qrel);
            p = ok ? p : 0.f;
            sc[nf][j] = p;
            ls += p;
          }
        }
        lsum[mf] += ls;
        int4 w0, w1;
        w0.x = cvtpk(sc[0][0], sc[0][1]); w0.y = cvtpk(sc[0][2], sc[0][3]);
        w0.z = cvtpk(sc[1][0], sc[1][1]); w0.w = cvtpk(sc[1][2], sc[1][3]);
        w1.x = cvtpk(sc[2][0], sc[2][1]); w1.y = cvtpk(sc[2][2], sc[2][3]);
        w1.z = cvtpk(sc[3][0], sc[3][1]); w1.w = cvtpk(sc[3][2], sc[3][3]);
        pf[mf][0] = __builtin_bit_cast(bf16x8, w0);
        pf[mf][1] = __builtin_bit_cast(bf16x8, w1);
      }
      __builtin_amdgcn_s_setprio(1);
      #pragma unroll
      for (int df=0;df<4;df++){
        bf16x8 vf0 = ld8swz(&Vs[cur][0], df*16+lr, lg*16);
        bf16x8 vf1 = ld8swz(&Vs[cur][0], df*16+lr, lg*16 + 64);
        if (act0){
          cacc[0][df] = __builtin_amdgcn_mfma_f32_16x16x32_bf16(pf[0][0], vf0, cacc[0][df],0,0,0);
          cacc[0][df] = __builtin_amdgcn_mfma_f32_16x16x32_bf16(pf[0][1], vf1, cacc[0][df],0,0,0);
        }
        cacc[1][df] = __builtin_amdgcn_mfma_f32_16x16x32_bf16(pf[1][0], vf0, cacc[1][df],0,0,0);
        cacc[1][df] = __builtin_amdgcn_mfma_f32_16x16x32_bf16(pf[1][1], vf1, cacc[1][df],0,0,0);
      }
      __builtin_amdgcn_s_setprio(0);
    }
    cur ^= 1;
  }

  #pragma unroll
  for (int mf=0;mf<2;mf++){
    const int rbm = mf ? rb1 : rb0;
    float T = lsum[mf];
    T += __shfl_xor(T, 16);
    T += __shfl_xor(T, 32);
    float lden[4];
    #pragma unroll
    for (int j=0;j<4;j++)
      lden[j] = __shfl(T, (lane & 48) | (lg*4 + j));
    #pragma unroll
    for (int df=0;df<4;df++)
      #pragma unroll
      for (int j=0;j<4;j++){
        int srow = rbm + lg*4 + j;
        int dd = df*16 + lr;
        float v = cacc[mf][df][j] / lden[j];
        if (lden[j] < 1e-30f) v = vmean[bh*64 + dd];
        ctxout[((size_t)b*S_ + srow)*D_ + h*DK_ + dd] = __float2bfloat16(v);
      }
  }
}

// ---------------- LayerNorm (bf16 input X2, f32 output) ----------------
__global__ __launch_bounds__(256) void ln_kernel(const bf16* __restrict__ X2,
    const float* __restrict__ gamma, const float* __restrict__ beta, float* __restrict__ out)
{
  const int row = blockIdx.x, tid = threadIdx.x;
  const int lane = tid&63, wid = tid>>6;
  const s16x4* xr = (const s16x4*)(X2 + (((size_t)row)<<10));
  s16x4 xv = xr[tid];
  f32x4 v;
  #pragma unroll
  for (int c=0;c<4;c++) v[c] = tof(xv[c]);
  float s  = v[0]+v[1]+v[2]+v[3];
  float s2 = v[0]*v[0]+v[1]*v[1]+v[2]*v[2]+v[3]*v[3];
  #pragma unroll
  for (int off=1;off<64;off<<=1){ s += __shfl_xor(s,off); s2 += __shfl_xor(s2,off); }
  __shared__ float red[8];
  if (lane==0){ red[wid]=s; red[wid+4]=s2; }
  __syncthreads();
  s  = red[0]+red[1]+red[2]+red[3];
  s2 = red[4]+red[5]+red[6]+red[7];
  float mu  = s*(1.f/1024.f);
  float var = s2*(1.f/1024.f) - mu*mu;
  float inv = rsqrtf(var + 1e-5f);
  f32x4 gv = ((const f32x4*)gamma)[tid], bv = ((const f32x4*)beta)[tid];
  f32x4 o;
  #pragma unroll
  for (int c=0;c<4;c++) o[c] = (v[c]-mu)*inv*gv[c] + bv[c];
  ((f32x4*)(out + (((size_t)row)<<10)))[tid] = o;
}

extern "C" void kernel_launch(void* const* d_in, const int* in_sizes, int n_in,
                              void* d_out, int out_size, void* d_ws, size_t ws_size,
                              hipStream_t stream) {
  const float* X   = (const float*)d_in[0];
  const int*   sm  = (const int*)d_in[1];
  const float* Wq  = (const float*)d_in[2];  const float* bq = (const float*)d_in[3];
  const float* Wk  = (const float*)d_in[4];  const float* bk = (const float*)d_in[5];
  const float* Wv  = (const float*)d_in[6];  const float* bv = (const float*)d_in[7];
  const float* Wo  = (const float*)d_in[8];  const float* bo = (const float*)d_in[9];
  const float* ga  = (const float*)d_in[10]; const float* be = (const float*)d_in[11];
  float* out = (float*)d_out;
  char* ws = (char*)d_ws;

  bf16* Xbf = (bf16*)(ws);                       // 16 MB
  bf16* Wqb = (bf16*)(ws + (16u<<20));           // 2 MB each, contiguous
  bf16* Wkb = (bf16*)(ws + (18u<<20));
  bf16* Wvb = (bf16*)(ws + (20u<<20));
  bf16* Wob = (bf16*)(ws + (22u<<20));
  bf16* Qh  = (bf16*)(ws + (24u<<20));           // 16 MB  [B,H,S,dk] (pre-scaled)
  bf16* Kh  = (bf16*)(ws + (40u<<20));           // 16 MB  [B,H,S,dk]
  bf16* Vth = (bf16*)(ws + (56u<<20));           // 16 MB  V^T [B,H,dk,S], sigma-permuted s
  bf16* Ctx = (bf16*)(ws + (72u<<20));           // 16 MB  [B,S,D]
  bf16* X2b = (bf16*)(ws + (24u<<20));           // 16 MB bf16, aliases Qh (dead after attn)
  float* vmean = (float*)(ws + (16u<<20));       // 32 KB, aliases Wqb (dead after gemm<0>)

  cast_all<<<6144,256,0,stream>>>(X, Wq, Wk, Wv, Wo, Xbf, Wqb);

  dim3 g1(M_/128, D_/128, 2);
  gemm128<0><<<g1,256,0,stream>>>(Xbf, Wqb, Wkb, bq, bk, Qh, Kh, nullptr);
  dim3 g1v(M_/128, D_/128, 1);
  gemm128<2><<<g1v,256,0,stream>>>(Xbf, Wvb, nullptr, bv, nullptr, Vth, nullptr, nullptr);

  vmean_kernel<<<B_*H_*DK_/4,256,0,stream>>>(Vth, vmean);

  dim3 g2(B_*H_, 4);
  attn_kernel<<<g2,512,0,stream>>>(Qh, Kh, Vth, sm, vmean, Ctx);

  dim3 g3(M_/128, D_/128, 1);
  gemm128<1><<<g3,256,0,stream>>>(Ctx, Wob, nullptr, bo, nullptr, X2b, nullptr, X);

  ln_kernel<<<M_,256,0,stream>>>(X2b, ga, be, out);
}

// Round 18
// 170.603 us; speedup vs baseline: 1.1182x; 1.1182x over previous
//
#include <hip/hip_runtime.h>
#include <hip/hip_bf16.h>

#define B_ 8
#define S_ 1024
#define D_ 1024
#define H_ 16
#define DK_ 64
#define M_ (B_*S_)

// 0.125 * log2(e): folds the 1/sqrt(dk) scale AND the exp->exp2 conversion into Q
#define QSCALE 0.1803368801111904f

typedef __attribute__((ext_vector_type(4))) float f32x4;
typedef __attribute__((ext_vector_type(8))) short bf16x8;
typedef __attribute__((ext_vector_type(4))) short s16x4;
typedef __hip_bfloat16 bf16;
typedef unsigned long long ull;

#define GLOAD_LDS16(gp, lp) __builtin_amdgcn_global_load_lds( \
    (const __attribute__((address_space(1))) void*)(gp), \
    (__attribute__((address_space(3))) void*)(lp), 16, 0, 0)

#define SBAR()   asm volatile("s_barrier" ::: "memory")
#define VMCNT(n) asm volatile("s_waitcnt vmcnt(" #n ")" ::: "memory")

__device__ __forceinline__ bf16x8 ld8(const bf16* p){ return *(const bf16x8*)p; }

__device__ __forceinline__ short bf16bits(float f){
  bf16 h = __float2bfloat16(f);
  return __builtin_bit_cast(short, h);
}
__device__ __forceinline__ float tof(short b){
  unsigned u = ((unsigned)(unsigned short)b) << 16;
  return __builtin_bit_cast(float, u);
}

// swizzled LDS fragment read: tile rows of 128B, XOR swizzle byte^=((row&7)<<4)
__device__ __forceinline__ bf16x8 ld8swz(const bf16* base, int row, int colb){
  int sw = colb ^ ((row & 7) << 4);
  return *(const bf16x8*)((const char*)base + row*128 + sw);
}

// DPP 16-lane add reduction — VALU pipe, no LDS traffic
template<int CTRL>
__device__ __forceinline__ float dppadd(float x){
  int m = __builtin_amdgcn_update_dpp(0, __builtin_bit_cast(int,x), CTRL, 0xF, 0xF, true);
  return x + __builtin_bit_cast(float,m);
}
__device__ __forceinline__ float red16add(float x){
  x = dppadd<0xB1>(x);   // quad_perm xor1
  x = dppadd<0x4E>(x);   // quad_perm xor2
  x = dppadd<0x141>(x);  // row_half_mirror
  x = dppadd<0x140>(x);  // row_mirror
  return x;
}

// ---------------- merged casts: X (blocks 0..4095) + 4 weight mats (4096..6143) ----------------
// last block additionally zeroes the vmean accumulator (lives in d_out[0:8192])
__global__ __launch_bounds__(256) void cast_all(const float* __restrict__ X,
    const float* __restrict__ w0, const float* __restrict__ w1,
    const float* __restrict__ w2, const float* __restrict__ w3,
    bf16* __restrict__ Xout, bf16* __restrict__ Wout, float* __restrict__ vmean){
  int bid = blockIdx.x;
  if (bid < 4096){
    int i = (bid*256 + threadIdx.x)*8;
    f32x4 a = *(const f32x4*)(X+i);
    f32x4 b = *(const f32x4*)(X+i+4);
    bf16x8 o;
    #pragma unroll
    for (int c=0;c<4;c++){ o[c] = bf16bits(a[c]); o[c+4] = bf16bits(b[c]); }
    *(bf16x8*)(Xout+i) = o;
  } else {
    int bb = bid - 4096;
    int sel = bb >> 9;
    const float* src = (sel==0)?w0:((sel==1)?w1:((sel==2)?w2:w3));
    int i = (((bb & 511)*256) + threadIdx.x)*8;
    f32x4 a = *(const f32x4*)(src+i);
    f32x4 b = *(const f32x4*)(src+i+4);
    bf16x8 o;
    #pragma unroll
    for (int c=0;c<4;c++){ o[c] = bf16bits(a[c]); o[c+4] = bf16bits(b[c]); }
    *(bf16x8*)(Wout + ((size_t)sel<<20) + i) = o;
    if (bid == 6143){
      for (int k=threadIdx.x; k<8192; k+=256) vmean[k] = 0.f;
    }
  }
}

// ---------------- GEMM: C = A * W^T (+bias), 128x128 tile, pipelined staging ----------------
// MODE 0: z=0 -> Q bf16 [B,H,S,dk] pre-scaled by QSCALE; z=1 -> K; z=2 -> V^T [B,H,dk,S]
//         z=2 also accumulates per-column sums (V+bias) into vmean via atomics.
// MODE 1: O -> x2b (bf16) = acc + bias + resid
// [benched r10-r15: QKV ~55 us @ ~930 TF]
template<int MODE>
__global__ __launch_bounds__(256) void gemm128(
    const bf16* __restrict__ A,
    const bf16* __restrict__ W0, const bf16* __restrict__ W1, const bf16* __restrict__ W2,
    const float* __restrict__ b0, const float* __restrict__ b1, const float* __restrict__ b2,
    bf16* __restrict__ o0, bf16* __restrict__ o1, bf16* __restrict__ o2,
    const float* __restrict__ resid, bf16* __restrict__ x2b, float* __restrict__ vmean)
{
  const bf16* Wsel = W0; const float* bsel = b0;
  if (MODE==0){
    int z = blockIdx.z;
    Wsel = (z==0)?W0:((z==1)?W1:W2);
    bsel = (z==0)?b0:((z==1)?b1:b2);
  }
  __shared__ bf16 smem[4*128*64];   // 64KB: buf0{A,B}, buf1{A,B}
  const int tid = threadIdx.x, wid = tid>>6, lane = tid&63;
  const int lr = lane&15, lg = lane>>4;
  const int m0 = blockIdx.x*128, n0 = blockIdx.y*128;
  const int wr = wid>>1, wc = wid&1;
  f32x4 acc[4][4] = {};

  auto STAGE = [&](int k0, int bsel_){
    #pragma unroll
    for (int c=0;c<4;c++){
      int ldsoff = ((c<<2)|wid)<<10;
      int off = ldsoff + (lane<<4);
      int row = off>>7;
      int colb = (off&127) ^ ((row&7)<<4);
      GLOAD_LDS16(A   + (((size_t)(m0+row))<<10) + k0 + (colb>>1), (char*)smem + bsel_*32768 + ldsoff);
      GLOAD_LDS16(Wsel+ (((size_t)(n0+row))<<10) + k0 + (colb>>1), (char*)smem + bsel_*32768 + 16384 + ldsoff);
    }
  };

  STAGE(0, 0);
  int cur = 0;
  for (int kt=0; kt<16; kt++){
    if (kt < 15){ STAGE((kt+1)<<6, cur^1); VMCNT(8); }  // tile kt's 8 loads (oldest) done
    else        { VMCNT(0); }
    SBAR();
    __builtin_amdgcn_sched_barrier(0);
    const bf16* Asb = smem + cur*16384;
    const bf16* Bsb = Asb + 8192;
    bf16x8 af[4][2], bfv[4][2];
    #pragma unroll
    for (int m=0;m<4;m++){
      int row = wr*64 + m*16 + lr;
      af[m][0] = ld8swz(Asb, row, lg*16);
      af[m][1] = ld8swz(Asb, row, lg*16 + 64);
    }
    #pragma unroll
    for (int n=0;n<4;n++){
      int row = wc*64 + n*16 + lr;
      bfv[n][0] = ld8swz(Bsb, row, lg*16);
      bfv[n][1] = ld8swz(Bsb, row, lg*16 + 64);
    }
    #pragma unroll
    for (int m=0;m<4;m++)
      #pragma unroll
      for (int n=0;n<4;n++){
        acc[m][n] = __builtin_amdgcn_mfma_f32_16x16x32_bf16(af[m][0], bfv[n][0], acc[m][n],0,0,0);
        acc[m][n] = __builtin_amdgcn_mfma_f32_16x16x32_bf16(af[m][1], bfv[n][1], acc[m][n],0,0,0);
      }
    __builtin_amdgcn_sched_barrier(0);
    SBAR();
    cur ^= 1;
  }

  if (MODE==0){
    if (blockIdx.z == 2){
      // vmean partial sums: col-sum over this block's 128 tokens (bias included 16x per thread,
      // totalling 1024*bias across all contributors). One atomic per col per wave (lg==0 lanes).
      const int b = m0 >> 10;
      #pragma unroll
      for (int n=0;n<4;n++){
        int col = n0 + wc*64 + n*16 + lr;
        float bias = bsel[col];
        float s = 16.f * bias;
        #pragma unroll
        for (int m=0;m<4;m++)
          #pragma unroll
          for (int j=0;j<4;j++) s += acc[m][n][j];
        s += __shfl_xor(s, 16);
        s += __shfl_xor(s, 32);
        if (lg == 0){
          int h = col>>6, dd = col&63;
          atomicAdd(vmean + ((b*H_ + h)<<6) + dd, s);
        }
      }
      // V^T epilogue: transpose 128x128 tile through LDS, write [B,H,dk,S]
      __syncthreads();
      #pragma unroll
      for (int n=0;n<4;n++){
        int c = wc*64 + n*16 + lr;
        float bias = bsel[n0 + c];
        #pragma unroll
        for (int m=0;m<4;m++){
          int r0 = wr*64 + m*16 + lg*4;
          s16x4 pk;
          #pragma unroll
          for (int j=0;j<4;j++) pk[j] = bf16bits(acc[m][n][j] + bias);
          *(s16x4*)((char*)smem + c*256 + ((r0*2) ^ ((c&7)<<4))) = pk;
        }
      }
      __syncthreads();
      #pragma unroll
      for (int q=0;q<8;q++){
        int idx = tid + q*256;
        int c = idx>>4, r8 = idx&15;
        bf16x8 vv = *(const bf16x8*)((char*)smem + c*256 + ((r8*16) ^ ((c&7)<<4)));
        int col = n0 + c;  int h = col>>6, dd = col&63;
        int row0 = m0 + r8*8;  int bb = row0>>10, s0 = row0&1023;
        *(bf16x8*)(o2 + ((((size_t)bb*H_ + h)*DK_ + dd)<<10) + s0) = vv;
      }
    } else {
      bf16* osel = (blockIdx.z==0) ? o0 : o1;
      const float qs = (blockIdx.z==0) ? QSCALE : 1.0f;   // pre-scale Q for exp2-domain scores
      #pragma unroll
      for (int n=0;n<4;n++){
        int col = n0 + wc*64 + n*16 + lr;
        float bias = bsel[col];
        int h = col>>6, dd = col&63;
        #pragma unroll
        for (int m=0;m<4;m++)
          #pragma unroll
          for (int j=0;j<4;j++){
            int row = m0 + wr*64 + m*16 + lg*4 + j;
            int bb = row>>10, s = row&1023;
            osel[((((size_t)bb*H_ + h)<<10) + s)*DK_ + dd] = __float2bfloat16((acc[m][n][j] + bias)*qs);
          }
      }
    }
  } else {
    // O-proj: x2b (bf16) = acc + bias + resid (f32)
    #pragma unroll
    for (int n=0;n<4;n++){
      int col = n0 + wc*64 + n*16 + lr;
      float bias = b0[col];
      #pragma unroll
      for (int m=0;m<4;m++)
        #pragma unroll
        for (int j=0;j<4;j++){
          int row = m0 + wr*64 + m*16 + lg*4 + j;
          size_t idx = (((size_t)row)<<10) + col;
          x2b[idx] = __float2bfloat16(acc[m][n][j] + bias + resid[idx]);
        }
    }
  }
}

// ---------------- fused causal attention: r15-benched structure (71.8 us) ----------------
// Single barrier per tile (VMCNT(0); SBAR; STAGE(t+1); compute(t)) + setprio around MFMA.
// Static-max exp2 softmax (Q pre-scaled); antidiagonal wave balance; DPP final reduce.
__global__ __launch_bounds__(512) void attn_kernel(
    const bf16* __restrict__ Q, const bf16* __restrict__ K, const bf16* __restrict__ Vt_g,
    const int* __restrict__ seqm, const float* __restrict__ vmean, bf16* __restrict__ ctxout)
{
  __shared__ bf16 Ks[2][64*64];   // K tile   [kv][d], swizzled, double-buffered
  __shared__ bf16 Vs[2][64*64];   // V^T tile [d][kv], swizzled, double-buffered
  __shared__ bf16 Ps[8][32*72];   // per-wave P scratch, padded
  __shared__ int msk[1024];
  const int tid = threadIdx.x, wid = tid>>6, lane = tid&63;
  const int lr = lane&15, lg = lane>>4;
  const int bh = blockIdx.x, xb = blockIdx.y;
  const int b = bh>>4, h = bh&15;
  const bf16* Qb  = Q    + (size_t)bh * S_ * DK_;
  const bf16* Kb  = K    + (size_t)bh * S_ * DK_;
  const bf16* Vtb = Vt_g + (size_t)bh * DK_ * S_;
  for (int i=tid;i<1024;i+=512) msk[i] = seqm[b*1024+i];

  const int g0 = 8*xb + wid;
  const int rb0 = g0*16;             // low group
  const int rb1 = (63 - g0)*16;      // high group (rb1 > rb0 always)
  bf16x8 qf[2][2];
  {
    const bf16* p0 = Qb + (size_t)(rb0+lr)*DK_ + lg*8;
    const bf16* p1 = Qb + (size_t)(rb1+lr)*DK_ + lg*8;
    qf[0][0] = ld8(p0); qf[0][1] = ld8(p0+32);
    qf[1][0] = ld8(p1); qf[1][1] = ld8(p1+32);
  }
  f32x4 cacc[2][4] = {};
  float lsum[2][4] = {};

  auto STAGE = [&](int t, int bsel){
    const int j0 = t*64;
    int off = (wid<<10) + (lane<<4);
    int row = off>>7;
    int colb = (off&127) ^ ((row&7)<<4);
    GLOAD_LDS16(Kb  + (size_t)(j0+row)*DK_ + (colb>>1), (char*)&Ks[bsel][0] + (wid<<10));
    GLOAD_LDS16(Vtb + (((size_t)row)<<10) + j0 + (colb>>1), (char*)&Vs[bsel][0] + (wid<<10));
  };

  STAGE(0, 0);
  __syncthreads();   // tile0 + msk ready

  // per-lane key-padding bitmask: bit i = msk[i*16 + lr]
  ull mbits = 0;
  #pragma unroll
  for (int i=0;i<64;i++) mbits |= ((ull)(msk[i*16+lr]!=0)) << i;

  const int bnt = ((1023 - 128*xb) >> 6) + 1;    // 16,14,12,10 for xb=0..3

  int cur = 0;
  for (int t=0; t<bnt; t++){
    VMCNT(0);    // this wave's STAGE(t) loads (issued last iter) have landed
    SBAR();      // everyone's stage(t) landed AND everyone finished reading buf cur^1
    if (t+1 < bnt) STAGE(t+1, cur^1);   // prefetch flies under compute(t)
    const int j0 = t*64;
    if (j0 <= rb1 + 15){
      const bool act0 = (j0 <= rb0 + 15);
      bf16x8 kf[4][2];
      #pragma unroll
      for (int nf=0;nf<4;nf++){
        kf[nf][0] = ld8swz(&Ks[cur][0], nf*16+lr, lg*16);
        kf[nf][1] = ld8swz(&Ks[cur][0], nf*16+lr, lg*16 + 64);
      }
      float madd[4];
      #pragma unroll
      for (int nf=0;nf<4;nf++)
        madd[nf] = ((mbits >> (t*4 + nf)) & 1ull) ? 0.f : -1.0e9f;

      #pragma unroll
      for (int mf=0;mf<2;mf++){
        if (mf==0 && !act0) continue;
        const int rbm = mf ? rb1 : rb0;
        const bool diag = (j0 + 63 > rbm);
        f32x4 sc[4] = {};
        __builtin_amdgcn_s_setprio(1);
        #pragma unroll
        for (int nf=0;nf<4;nf++){
          sc[nf] = __builtin_amdgcn_mfma_f32_16x16x32_bf16(qf[mf][0], kf[nf][0], sc[nf],0,0,0);
          sc[nf] = __builtin_amdgcn_mfma_f32_16x16x32_bf16(qf[mf][1], kf[nf][1], sc[nf],0,0,0);
        }
        __builtin_amdgcn_s_setprio(0);
        #pragma unroll
        for (int j=0;j<4;j++){
          int row = rbm + lg*4 + j;
          float ps = 0.f;
          #pragma unroll
          for (int nf=0;nf<4;nf++){
            float s = sc[nf][j] + madd[nf];
            if (diag){
              int col = j0 + nf*16 + lr;
              s = (col <= row) ? s : -1.0e9f;
            }
            float p = exp2f(s);
            sc[nf][j] = p;
            ps += p;
          }
          lsum[mf][j] += ps;
        }
        #pragma unroll
        for (int nf=0;nf<4;nf++)
          #pragma unroll
          for (int j=0;j<4;j++)
            Ps[wid][(mf*16+lg*4+j)*72 + nf*16+lr] = __float2bfloat16(sc[nf][j]);
      }
      // PV
      bf16x8 pf[2][2];
      #pragma unroll
      for (int mf=0;mf<2;mf++){
        if (mf==0 && !act0) continue;
        const bf16* p = &Ps[wid][(mf*16+lr)*72 + lg*8];
        pf[mf][0] = *(const bf16x8*)p; pf[mf][1] = *(const bf16x8*)(p+32);
      }
      __builtin_amdgcn_s_setprio(1);
      #pragma unroll
      for (int df=0;df<4;df++){
        #pragma unroll
        for (int kk=0;kk<2;kk++){
          bf16x8 vf = ld8swz(&Vs[cur][0], df*16+lr, lg*16 + kk*64);
          if (act0)
            cacc[0][df] = __builtin_amdgcn_mfma_f32_16x16x32_bf16(pf[0][kk], vf, cacc[0][df],0,0,0);
          cacc[1][df] = __builtin_amdgcn_mfma_f32_16x16x32_bf16(pf[1][kk], vf, cacc[1][df],0,0,0);
        }
      }
      __builtin_amdgcn_s_setprio(0);
    }
    cur ^= 1;
  }

  #pragma unroll
  for (int mf=0;mf<2;mf++){
    const int rbm = mf ? rb1 : rb0;
    float lt[4];
    #pragma unroll
    for (int j=0;j<4;j++) lt[j] = red16add(lsum[mf][j]);
    #pragma unroll
    for (int df=0;df<4;df++)
      #pragma unroll
      for (int j=0;j<4;j++){
        int srow = rbm + lg*4 + j;
        int dd = df*16 + lr;
        float v = cacc[mf][df][j] / lt[j];
        if (lt[j] <= 1.0e-30f) v = vmean[bh*64 + dd] * (1.f/1024.f);  // fully-masked row
        ctxout[((size_t)b*S_ + srow)*D_ + h*DK_ + dd] = __float2bfloat16(v);
      }
  }
}

// ---------------- LayerNorm (bf16 input X2, f32 output) ----------------
__global__ __launch_bounds__(256) void ln_kernel(const bf16* __restrict__ X2,
    const float* __restrict__ gamma, const float* __restrict__ beta, float* __restrict__ out)
{
  const int row = blockIdx.x, tid = threadIdx.x;
  const int lane = tid&63, wid = tid>>6;
  const s16x4* xr = (const s16x4*)(X2 + (((size_t)row)<<10));
  s16x4 xv = xr[tid];
  f32x4 v;
  #pragma unroll
  for (int c=0;c<4;c++) v[c] = tof(xv[c]);
  float s  = v[0]+v[1]+v[2]+v[3];
  float s2 = v[0]*v[0]+v[1]*v[1]+v[2]*v[2]+v[3]*v[3];
  #pragma unroll
  for (int off=1;off<64;off<<=1){ s += __shfl_xor(s,off); s2 += __shfl_xor(s2,off); }
  __shared__ float red[8];
  if (lane==0){ red[wid]=s; red[wid+4]=s2; }
  __syncthreads();
  s  = red[0]+red[1]+red[2]+red[3];
  s2 = red[4]+red[5]+red[6]+red[7];
  float mu  = s*(1.f/1024.f);
  float var = s2*(1.f/1024.f) - mu*mu;
  float inv = rsqrtf(var + 1e-5f);
  f32x4 gv = ((const f32x4*)gamma)[tid], bv = ((const f32x4*)beta)[tid];
  f32x4 o;
  #pragma unroll
  for (int c=0;c<4;c++) o[c] = (v[c]-mu)*inv*gv[c] + bv[c];
  ((f32x4*)(out + (((size_t)row)<<10)))[tid] = o;
}

extern "C" void kernel_launch(void* const* d_in, const int* in_sizes, int n_in,
                              void* d_out, int out_size, void* d_ws, size_t ws_size,
                              hipStream_t stream) {
  const float* X   = (const float*)d_in[0];
  const int*   sm  = (const int*)d_in[1];
  const float* Wq  = (const float*)d_in[2];  const float* bq = (const float*)d_in[3];
  const float* Wk  = (const float*)d_in[4];  const float* bk = (const float*)d_in[5];
  const float* Wv  = (const float*)d_in[6];  const float* bv = (const float*)d_in[7];
  const float* Wo  = (const float*)d_in[8];  const float* bo = (const float*)d_in[9];
  const float* ga  = (const float*)d_in[10]; const float* be = (const float*)d_in[11];
  float* out = (float*)d_out;
  char* ws = (char*)d_ws;

  bf16* Xbf = (bf16*)(ws);                       // 16 MB
  bf16* Wqb = (bf16*)(ws + (16u<<20));           // 2 MB each, contiguous
  bf16* Wkb = (bf16*)(ws + (18u<<20));
  bf16* Wvb = (bf16*)(ws + (20u<<20));
  bf16* Wob = (bf16*)(ws + (22u<<20));
  bf16* Qh  = (bf16*)(ws + (24u<<20));           // 16 MB  [B,H,S,dk] (pre-scaled)
  bf16* Kh  = (bf16*)(ws + (40u<<20));           // 16 MB  [B,H,S,dk]
  bf16* Vth = (bf16*)(ws + (56u<<20));           // 16 MB  V^T [B,H,dk,S]
  bf16* Ctx = (bf16*)(ws + (72u<<20));           // 16 MB  [B,S,D]
  bf16* X2b = (bf16*)(ws + (24u<<20));           // 16 MB bf16, aliases Qh (dead after attn)
  // vmean scratch: first 32KB of d_out — zeroed by cast_all, consumed by attn,
  // fully overwritten by ln_kernel at the end.
  float* vmean = (float*)d_out;

  cast_all<<<6144,256,0,stream>>>(X, Wq, Wk, Wv, Wo, Xbf, Wqb, vmean);

  dim3 g1(M_/128, D_/128, 3);
  gemm128<0><<<g1,256,0,stream>>>(Xbf, Wqb,Wkb,Wvb, bq,bk,bv, Qh,Kh,Vth,
                                  nullptr, nullptr, vmean);

  dim3 g2(B_*H_, 4);
  attn_kernel<<<g2,512,0,stream>>>(Qh, Kh, Vth, sm, vmean, Ctx);

  dim3 g3(M_/128, D_/128, 1);
  gemm128<1><<<g3,256,0,stream>>>(Ctx, Wob,nullptr,nullptr, bo,nullptr,nullptr,
                                  nullptr,nullptr,nullptr, X, X2b, nullptr);

  ln_kernel<<<M_,256,0,stream>>>(X2b, ga, be, out);
}

// Round 19
// 169.106 us; speedup vs baseline: 1.1281x; 1.0089x over previous
//
#include <hip/hip_runtime.h>
#include <hip/hip_bf16.h>

#define B_ 8
#define S_ 1024
#define D_ 1024
#define H_ 16
#define DK_ 64
#define M_ (B_*S_)

// 0.125 * log2(e): folds the 1/sqrt(dk) scale AND the exp->exp2 conversion into Q
#define QSCALE 0.1803368801111904f

typedef __attribute__((ext_vector_type(4))) float f32x4;
typedef __attribute__((ext_vector_type(8))) short bf16x8;
typedef __attribute__((ext_vector_type(4))) short s16x4;
typedef __hip_bfloat16 bf16;
typedef unsigned long long ull;

#define GLOAD_LDS16(gp, lp) __builtin_amdgcn_global_load_lds( \
    (const __attribute__((address_space(1))) void*)(gp), \
    (__attribute__((address_space(3))) void*)(lp), 16, 0, 0)

#define SBAR()   asm volatile("s_barrier" ::: "memory")
#define VMCNT(n) asm volatile("s_waitcnt vmcnt(" #n ")" ::: "memory")

__device__ __forceinline__ bf16x8 ld8(const bf16* p){ return *(const bf16x8*)p; }

__device__ __forceinline__ short bf16bits(float f){
  bf16 h = __float2bfloat16(f);
  return __builtin_bit_cast(short, h);
}
__device__ __forceinline__ float tof(short b){
  unsigned u = ((unsigned)(unsigned short)b) << 16;
  return __builtin_bit_cast(float, u);
}

// swizzled LDS fragment read: tile rows of 128B, XOR swizzle byte^=((row&7)<<4)
__device__ __forceinline__ bf16x8 ld8swz(const bf16* base, int row, int colb){
  int sw = colb ^ ((row & 7) << 4);
  return *(const bf16x8*)((const char*)base + row*128 + sw);
}

// DPP 16-lane add reduction — VALU pipe, no LDS traffic
template<int CTRL>
__device__ __forceinline__ float dppadd(float x){
  int m = __builtin_amdgcn_update_dpp(0, __builtin_bit_cast(int,x), CTRL, 0xF, 0xF, true);
  return x + __builtin_bit_cast(float,m);
}
__device__ __forceinline__ float red16add(float x){
  x = dppadd<0xB1>(x);   // quad_perm xor1
  x = dppadd<0x4E>(x);   // quad_perm xor2
  x = dppadd<0x141>(x);  // row_half_mirror
  x = dppadd<0x140>(x);  // row_mirror
  return x;
}

// ---------------- merged casts: X (blocks 0..4095) + 4 weight mats (4096..6143) ----------------
// last block additionally zeroes the vmean accumulator (lives in d_out[0:8192])
__global__ __launch_bounds__(256) void cast_all(const float* __restrict__ X,
    const float* __restrict__ w0, const float* __restrict__ w1,
    const float* __restrict__ w2, const float* __restrict__ w3,
    bf16* __restrict__ Xout, bf16* __restrict__ Wout, float* __restrict__ vmean){
  int bid = blockIdx.x;
  if (bid < 4096){
    int i = (bid*256 + threadIdx.x)*8;
    f32x4 a = *(const f32x4*)(X+i);
    f32x4 b = *(const f32x4*)(X+i+4);
    bf16x8 o;
    #pragma unroll
    for (int c=0;c<4;c++){ o[c] = bf16bits(a[c]); o[c+4] = bf16bits(b[c]); }
    *(bf16x8*)(Xout+i) = o;
  } else {
    int bb = bid - 4096;
    int sel = bb >> 9;
    const float* src = (sel==0)?w0:((sel==1)?w1:((sel==2)?w2:w3));
    int i = (((bb & 511)*256) + threadIdx.x)*8;
    f32x4 a = *(const f32x4*)(src+i);
    f32x4 b = *(const f32x4*)(src+i+4);
    bf16x8 o;
    #pragma unroll
    for (int c=0;c<4;c++){ o[c] = bf16bits(a[c]); o[c+4] = bf16bits(b[c]); }
    *(bf16x8*)(Wout + ((size_t)sel<<20) + i) = o;
    if (bid == 6143){
      for (int k=threadIdx.x; k<8192; k+=256) vmean[k] = 0.f;
    }
  }
}

// ---------------- GEMM: C = A * W^T (+bias), 128x128 tile, pipelined staging ----------------
// MODE 0: z=0 -> Q bf16 [B,H,S,dk] pre-scaled by QSCALE; z=1 -> K; z=2 -> V^T [B,H,dk,S]
//         z=2 also accumulates per-column sums (V+bias) into vmean via atomics.
// MODE 1: O -> x2b (bf16) = acc + bias + resid(bf16 Xbf)
// [benched r10-r18: QKV ~55 us @ ~930 TF]
template<int MODE>
__global__ __launch_bounds__(256) void gemm128(
    const bf16* __restrict__ A,
    const bf16* __restrict__ W0, const bf16* __restrict__ W1, const bf16* __restrict__ W2,
    const float* __restrict__ b0, const float* __restrict__ b1, const float* __restrict__ b2,
    bf16* __restrict__ o0, bf16* __restrict__ o1, bf16* __restrict__ o2,
    const bf16* __restrict__ resid, bf16* __restrict__ x2b, float* __restrict__ vmean)
{
  const bf16* Wsel = W0; const float* bsel = b0;
  if (MODE==0){
    int z = blockIdx.z;
    Wsel = (z==0)?W0:((z==1)?W1:W2);
    bsel = (z==0)?b0:((z==1)?b1:b2);
  }
  __shared__ bf16 smem[4*128*64];   // 64KB: buf0{A,B}, buf1{A,B}
  const int tid = threadIdx.x, wid = tid>>6, lane = tid&63;
  const int lr = lane&15, lg = lane>>4;
  const int m0 = blockIdx.x*128, n0 = blockIdx.y*128;
  const int wr = wid>>1, wc = wid&1;
  f32x4 acc[4][4] = {};

  auto STAGE = [&](int k0, int bsel_){
    #pragma unroll
    for (int c=0;c<4;c++){
      int ldsoff = ((c<<2)|wid)<<10;
      int off = ldsoff + (lane<<4);
      int row = off>>7;
      int colb = (off&127) ^ ((row&7)<<4);
      GLOAD_LDS16(A   + (((size_t)(m0+row))<<10) + k0 + (colb>>1), (char*)smem + bsel_*32768 + ldsoff);
      GLOAD_LDS16(Wsel+ (((size_t)(n0+row))<<10) + k0 + (colb>>1), (char*)smem + bsel_*32768 + 16384 + ldsoff);
    }
  };

  STAGE(0, 0);
  int cur = 0;
  for (int kt=0; kt<16; kt++){
    if (kt < 15){ STAGE((kt+1)<<6, cur^1); VMCNT(8); }  // tile kt's 8 loads (oldest) done
    else        { VMCNT(0); }
    SBAR();
    __builtin_amdgcn_sched_barrier(0);
    const bf16* Asb = smem + cur*16384;
    const bf16* Bsb = Asb + 8192;
    bf16x8 af[4][2], bfv[4][2];
    #pragma unroll
    for (int m=0;m<4;m++){
      int row = wr*64 + m*16 + lr;
      af[m][0] = ld8swz(Asb, row, lg*16);
      af[m][1] = ld8swz(Asb, row, lg*16 + 64);
    }
    #pragma unroll
    for (int n=0;n<4;n++){
      int row = wc*64 + n*16 + lr;
      bfv[n][0] = ld8swz(Bsb, row, lg*16);
      bfv[n][1] = ld8swz(Bsb, row, lg*16 + 64);
    }
    #pragma unroll
    for (int m=0;m<4;m++)
      #pragma unroll
      for (int n=0;n<4;n++){
        acc[m][n] = __builtin_amdgcn_mfma_f32_16x16x32_bf16(af[m][0], bfv[n][0], acc[m][n],0,0,0);
        acc[m][n] = __builtin_amdgcn_mfma_f32_16x16x32_bf16(af[m][1], bfv[n][1], acc[m][n],0,0,0);
      }
    __builtin_amdgcn_sched_barrier(0);
    SBAR();
    cur ^= 1;
  }

  if (MODE==0){
    if (blockIdx.z == 2){
      // vmean partial sums: col-sum over this block's 128 tokens (bias included 16x per thread,
      // totalling 1024*bias across all contributors). One atomic per col per wave (lg==0 lanes).
      const int b = m0 >> 10;
      #pragma unroll
      for (int n=0;n<4;n++){
        int col = n0 + wc*64 + n*16 + lr;
        float bias = bsel[col];
        float s = 16.f * bias;
        #pragma unroll
        for (int m=0;m<4;m++)
          #pragma unroll
          for (int j=0;j<4;j++) s += acc[m][n][j];
        s += __shfl_xor(s, 16);
        s += __shfl_xor(s, 32);
        if (lg == 0){
          int h = col>>6, dd = col&63;
          atomicAdd(vmean + ((b*H_ + h)<<6) + dd, s);
        }
      }
      // V^T epilogue: transpose 128x128 tile through LDS, write [B,H,dk,S]
      __syncthreads();
      #pragma unroll
      for (int n=0;n<4;n++){
        int c = wc*64 + n*16 + lr;
        float bias = bsel[n0 + c];
        #pragma unroll
        for (int m=0;m<4;m++){
          int r0 = wr*64 + m*16 + lg*4;
          s16x4 pk;
          #pragma unroll
          for (int j=0;j<4;j++) pk[j] = bf16bits(acc[m][n][j] + bias);
          *(s16x4*)((char*)smem + c*256 + ((r0*2) ^ ((c&7)<<4))) = pk;
        }
      }
      __syncthreads();
      #pragma unroll
      for (int q=0;q<8;q++){
        int idx = tid + q*256;
        int c = idx>>4, r8 = idx&15;
        bf16x8 vv = *(const bf16x8*)((char*)smem + c*256 + ((r8*16) ^ ((c&7)<<4)));
        int col = n0 + c;  int h = col>>6, dd = col&63;
        int row0 = m0 + r8*8;  int bb = row0>>10, s0 = row0&1023;
        *(bf16x8*)(o2 + ((((size_t)bb*H_ + h)*DK_ + dd)<<10) + s0) = vv;
      }
    } else {
      bf16* osel = (blockIdx.z==0) ? o0 : o1;
      const float qs = (blockIdx.z==0) ? QSCALE : 1.0f;   // pre-scale Q for exp2-domain scores
      #pragma unroll
      for (int n=0;n<4;n++){
        int col = n0 + wc*64 + n*16 + lr;
        float bias = bsel[col];
        int h = col>>6, dd = col&63;
        #pragma unroll
        for (int m=0;m<4;m++)
          #pragma unroll
          for (int j=0;j<4;j++){
            int row = m0 + wr*64 + m*16 + lg*4 + j;
            int bb = row>>10, s = row&1023;
            osel[((((size_t)bb*H_ + h)<<10) + s)*DK_ + dd] = __float2bfloat16((acc[m][n][j] + bias)*qs);
          }
      }
    }
  } else {
    // O-proj: x2b (bf16) = acc + bias + resid (bf16 Xbf — half the resid traffic of f32 X)
    #pragma unroll
    for (int n=0;n<4;n++){
      int col = n0 + wc*64 + n*16 + lr;
      float bias = b0[col];
      #pragma unroll
      for (int m=0;m<4;m++)
        #pragma unroll
        for (int j=0;j<4;j++){
          int row = m0 + wr*64 + m*16 + lg*4 + j;
          size_t idx = (((size_t)row)<<10) + col;
          x2b[idx] = __float2bfloat16(acc[m][n][j] + bias + tof(__builtin_bit_cast(short, resid[idx])));
        }
    }
  }
}

// ---------------- fused causal attention: r15/r18-benched structure (68 us) ----------------
// Single barrier per tile (VMCNT(0); SBAR; STAGE(t+1); compute(t)) + setprio around MFMA.
// Static-max exp2 softmax (Q pre-scaled); antidiagonal wave balance; DPP final reduce.
__global__ __launch_bounds__(512) void attn_kernel(
    const bf16* __restrict__ Q, const bf16* __restrict__ K, const bf16* __restrict__ Vt_g,
    const int* __restrict__ seqm, const float* __restrict__ vmean, bf16* __restrict__ ctxout)
{
  __shared__ bf16 Ks[2][64*64];   // K tile   [kv][d], swizzled, double-buffered
  __shared__ bf16 Vs[2][64*64];   // V^T tile [d][kv], swizzled, double-buffered
  __shared__ bf16 Ps[8][32*72];   // per-wave P scratch, padded
  __shared__ int msk[1024];
  const int tid = threadIdx.x, wid = tid>>6, lane = tid&63;
  const int lr = lane&15, lg = lane>>4;
  const int bh = blockIdx.x, xb = blockIdx.y;
  const int b = bh>>4, h = bh&15;
  const bf16* Qb  = Q    + (size_t)bh * S_ * DK_;
  const bf16* Kb  = K    + (size_t)bh * S_ * DK_;
  const bf16* Vtb = Vt_g + (size_t)bh * DK_ * S_;
  for (int i=tid;i<1024;i+=512) msk[i] = seqm[b*1024+i];

  const int g0 = 8*xb + wid;
  const int rb0 = g0*16;             // low group
  const int rb1 = (63 - g0)*16;      // high group (rb1 > rb0 always)
  bf16x8 qf[2][2];
  {
    const bf16* p0 = Qb + (size_t)(rb0+lr)*DK_ + lg*8;
    const bf16* p1 = Qb + (size_t)(rb1+lr)*DK_ + lg*8;
    qf[0][0] = ld8(p0); qf[0][1] = ld8(p0+32);
    qf[1][0] = ld8(p1); qf[1][1] = ld8(p1+32);
  }
  f32x4 cacc[2][4] = {};
  float lsum[2][4] = {};

  auto STAGE = [&](int t, int bsel){
    const int j0 = t*64;
    int off = (wid<<10) + (lane<<4);
    int row = off>>7;
    int colb = (off&127) ^ ((row&7)<<4);
    GLOAD_LDS16(Kb  + (size_t)(j0+row)*DK_ + (colb>>1), (char*)&Ks[bsel][0] + (wid<<10));
    GLOAD_LDS16(Vtb + (((size_t)row)<<10) + j0 + (colb>>1), (char*)&Vs[bsel][0] + (wid<<10));
  };

  STAGE(0, 0);
  __syncthreads();   // tile0 + msk ready

  // per-lane key-padding bitmask: bit i = msk[i*16 + lr]
  ull mbits = 0;
  #pragma unroll
  for (int i=0;i<64;i++) mbits |= ((ull)(msk[i*16+lr]!=0)) << i;

  const int bnt = ((1023 - 128*xb) >> 6) + 1;    // 16,14,12,10 for xb=0..3

  int cur = 0;
  for (int t=0; t<bnt; t++){
    VMCNT(0);    // this wave's STAGE(t) loads (issued last iter) have landed
    SBAR();      // everyone's stage(t) landed AND everyone finished reading buf cur^1
    if (t+1 < bnt) STAGE(t+1, cur^1);   // prefetch flies under compute(t)
    const int j0 = t*64;
    if (j0 <= rb1 + 15){
      const bool act0 = (j0 <= rb0 + 15);
      bf16x8 kf[4][2];
      #pragma unroll
      for (int nf=0;nf<4;nf++){
        kf[nf][0] = ld8swz(&Ks[cur][0], nf*16+lr, lg*16);
        kf[nf][1] = ld8swz(&Ks[cur][0], nf*16+lr, lg*16 + 64);
      }
      float madd[4];
      #pragma unroll
      for (int nf=0;nf<4;nf++)
        madd[nf] = ((mbits >> (t*4 + nf)) & 1ull) ? 0.f : -1.0e9f;

      #pragma unroll
      for (int mf=0;mf<2;mf++){
        if (mf==0 && !act0) continue;
        const int rbm = mf ? rb1 : rb0;
        const bool diag = (j0 + 63 > rbm);
        f32x4 sc[4] = {};
        __builtin_amdgcn_s_setprio(1);
        #pragma unroll
        for (int nf=0;nf<4;nf++){
          sc[nf] = __builtin_amdgcn_mfma_f32_16x16x32_bf16(qf[mf][0], kf[nf][0], sc[nf],0,0,0);
          sc[nf] = __builtin_amdgcn_mfma_f32_16x16x32_bf16(qf[mf][1], kf[nf][1], sc[nf],0,0,0);
        }
        __builtin_amdgcn_s_setprio(0);
        #pragma unroll
        for (int j=0;j<4;j++){
          int row = rbm + lg*4 + j;
          float ps = 0.f;
          #pragma unroll
          for (int nf=0;nf<4;nf++){
            float s = sc[nf][j] + madd[nf];
            if (diag){
              int col = j0 + nf*16 + lr;
              s = (col <= row) ? s : -1.0e9f;
            }
            float p = exp2f(s);
            sc[nf][j] = p;
            ps += p;
          }
          lsum[mf][j] += ps;
        }
        #pragma unroll
        for (int nf=0;nf<4;nf++)
          #pragma unroll
          for (int j=0;j<4;j++)
            Ps[wid][(mf*16+lg*4+j)*72 + nf*16+lr] = __float2bfloat16(sc[nf][j]);
      }
      // PV
      bf16x8 pf[2][2];
      #pragma unroll
      for (int mf=0;mf<2;mf++){
        if (mf==0 && !act0) continue;
        const bf16* p = &Ps[wid][(mf*16+lr)*72 + lg*8];
        pf[mf][0] = *(const bf16x8*)p; pf[mf][1] = *(const bf16x8*)(p+32);
      }
      __builtin_amdgcn_s_setprio(1);
      #pragma unroll
      for (int df=0;df<4;df++){
        #pragma unroll
        for (int kk=0;kk<2;kk++){
          bf16x8 vf = ld8swz(&Vs[cur][0], df*16+lr, lg*16 + kk*64);
          if (act0)
            cacc[0][df] = __builtin_amdgcn_mfma_f32_16x16x32_bf16(pf[0][kk], vf, cacc[0][df],0,0,0);
          cacc[1][df] = __builtin_amdgcn_mfma_f32_16x16x32_bf16(pf[1][kk], vf, cacc[1][df],0,0,0);
        }
      }
      __builtin_amdgcn_s_setprio(0);
    }
    cur ^= 1;
  }

  #pragma unroll
  for (int mf=0;mf<2;mf++){
    const int rbm = mf ? rb1 : rb0;
    float lt[4];
    #pragma unroll
    for (int j=0;j<4;j++) lt[j] = red16add(lsum[mf][j]);
    #pragma unroll
    for (int df=0;df<4;df++)
      #pragma unroll
      for (int j=0;j<4;j++){
        int srow = rbm + lg*4 + j;
        int dd = df*16 + lr;
        float v = cacc[mf][df][j] / lt[j];
        if (lt[j] <= 1.0e-30f) v = vmean[bh*64 + dd] * (1.f/1024.f);  // fully-masked row
        ctxout[((size_t)b*S_ + srow)*D_ + h*DK_ + dd] = __float2bfloat16(v);
      }
  }
}

// ---------------- LayerNorm (bf16 input X2, f32 output) ----------------
__global__ __launch_bounds__(256) void ln_kernel(const bf16* __restrict__ X2,
    const float* __restrict__ gamma, const float* __restrict__ beta, float* __restrict__ out)
{
  const int row = blockIdx.x, tid = threadIdx.x;
  const int lane = tid&63, wid = tid>>6;
  const s16x4* xr = (const s16x4*)(X2 + (((size_t)row)<<10));
  s16x4 xv = xr[tid];
  f32x4 v;
  #pragma unroll
  for (int c=0;c<4;c++) v[c] = tof(xv[c]);
  float s  = v[0]+v[1]+v[2]+v[3];
  float s2 = v[0]*v[0]+v[1]*v[1]+v[2]*v[2]+v[3]*v[3];
  #pragma unroll
  for (int off=1;off<64;off<<=1){ s += __shfl_xor(s,off); s2 += __shfl_xor(s2,off); }
  __shared__ float red[8];
  if (lane==0){ red[wid]=s; red[wid+4]=s2; }
  __syncthreads();
  s  = red[0]+red[1]+red[2]+red[3];
  s2 = red[4]+red[5]+red[6]+red[7];
  float mu  = s*(1.f/1024.f);
  float var = s2*(1.f/1024.f) - mu*mu;
  float inv = rsqrtf(var + 1e-5f);
  f32x4 gv = ((const f32x4*)gamma)[tid], bv = ((const f32x4*)beta)[tid];
  f32x4 o;
  #pragma unroll
  for (int c=0;c<4;c++) o[c] = (v[c]-mu)*inv*gv[c] + bv[c];
  ((f32x4*)(out + (((size_t)row)<<10)))[tid] = o;
}

extern "C" void kernel_launch(void* const* d_in, const int* in_sizes, int n_in,
                              void* d_out, int out_size, void* d_ws, size_t ws_size,
                              hipStream_t stream) {
  const float* X   = (const float*)d_in[0];
  const int*   sm  = (const int*)d_in[1];
  const float* Wq  = (const float*)d_in[2];  const float* bq = (const float*)d_in[3];
  const float* Wk  = (const float*)d_in[4];  const float* bk = (const float*)d_in[5];
  const float* Wv  = (const float*)d_in[6];  const float* bv = (const float*)d_in[7];
  const float* Wo  = (const float*)d_in[8];  const float* bo = (const float*)d_in[9];
  const float* ga  = (const float*)d_in[10]; const float* be = (const float*)d_in[11];
  float* out = (float*)d_out;
  char* ws = (char*)d_ws;

  bf16* Xbf = (bf16*)(ws);                       // 16 MB
  bf16* Wqb = (bf16*)(ws + (16u<<20));           // 2 MB each, contiguous
  bf16* Wkb = (bf16*)(ws + (18u<<20));
  bf16* Wvb = (bf16*)(ws + (20u<<20));
  bf16* Wob = (bf16*)(ws + (22u<<20));
  bf16* Qh  = (bf16*)(ws + (24u<<20));           // 16 MB  [B,H,S,dk] (pre-scaled)
  bf16* Kh  = (bf16*)(ws + (40u<<20));           // 16 MB  [B,H,S,dk]
  bf16* Vth = (bf16*)(ws + (56u<<20));           // 16 MB  V^T [B,H,dk,S]
  bf16* Ctx = (bf16*)(ws + (72u<<20));           // 16 MB  [B,S,D]
  bf16* X2b = (bf16*)(ws + (24u<<20));           // 16 MB bf16, aliases Qh (dead after attn)
  // vmean scratch: first 32KB of d_out — zeroed by cast_all, consumed by attn,
  // fully overwritten by ln_kernel at the end.
  float* vmean = (float*)d_out;

  cast_all<<<6144,256,0,stream>>>(X, Wq, Wk, Wv, Wo, Xbf, Wqb, vmean);

  dim3 g1(M_/128, D_/128, 3);
  gemm128<0><<<g1,256,0,stream>>>(Xbf, Wqb,Wkb,Wvb, bq,bk,bv, Qh,Kh,Vth,
                                  nullptr, nullptr, vmean);

  dim3 g2(B_*H_, 4);
  attn_kernel<<<g2,512,0,stream>>>(Qh, Kh, Vth, sm, vmean, Ctx);

  dim3 g3(M_/128, D_/128, 1);
  gemm128<1><<<g3,256,0,stream>>>(Ctx, Wob,nullptr,nullptr, bo,nullptr,nullptr,
                                  nullptr,nullptr,nullptr, Xbf, X2b, nullptr);

  ln_kernel<<<M_,256,0,stream>>>(X2b, ga, be, out);
}